// Round 4
// baseline (115.214 us; speedup 1.0000x reference)
//
#include <hip/hip_runtime.h>
#include <math.h>

// Problem constants (match reference)
#define BATCH 16384
#define NN    1024
#define NI    128
#define NO    64
#define REFR  0.9f

typedef float  f32x4  __attribute__((ext_vector_type(4)));
typedef __bf16 bf16x8 __attribute__((ext_vector_type(8)));

// ---------------------------------------------------------------------------
// Kernel 1: pack W[:, 960:1024] into bf16 B-fragments for mfma_f32_16x16x32_bf16,
// WITH the refractory scale folded in: rows k in [128,960) are pre-multiplied
// by 0.9 (scale is per-k, so scaling W rows == scaling states cols).
// Thread map: k = idx>>6, n = idx&63 -> 64 lanes read 256 B contiguous per
// W row (coalesced); the 2 B frag writes scatter (stores don't stall).
// Frag layout (m89 B-layout): element j of frag[(kc*4+tn)*64 + l]
//   = W[kc*32 + (l>>4)*8 + j][960 + tn*16 + (l&15)]
// ---------------------------------------------------------------------------
__global__ __launch_bounds__(256) void pack_w_kernel(const float* __restrict__ W,
                                                     __bf16* __restrict__ wsB) {
    int idx = blockIdx.x * 256 + threadIdx.x;   // 0 .. 65535
    int k = idx >> 6;        // 0..1023
    int n = idx & 63;        // 0..63
    float v = W[(size_t)k * NN + (NN - NO) + n];
    int kc = k >> 5;
    if (kc >= 4 && kc < 30) v *= REFR;          // fold refractory factor
    int kk = k & 31;
    int r3 = kk >> 3;
    int j  = kk & 7;
    int tn = n >> 4;
    int l  = r3 * 16 + (n & 15);
    wsB[(size_t)(((kc * 4 + tn) * 64 + l) * 8 + j)] = (__bf16)v;
}

__device__ inline float activate(float x, int id) {
    if (id == 0) return fmaxf(x, 0.0f);
    if (id == 1) return tanhf(x);
    if (id == 2) return 1.0f / (1.0f + __expf(-x));
    return x;
}

// ---------------------------------------------------------------------------
// Kernel 2: fused input-assign + GEMM (M=16384, N=64, K=1024) + bias +
// heterogeneous activation. K-split x4 across waves; M-block x2 per wave:
// each wave computes 32 rows (two 16-row A-tiles) against one shared B-frag
// load -> halves block count, L2 B-traffic, and barrier/epilogue instances.
// 512 blocks = 2 blocks/CU; __launch_bounds__(256,2) frees VGPRs for hoisting.
// ---------------------------------------------------------------------------
__global__ __launch_bounds__(256, 2) void fused_rnn_kernel(
    const float* __restrict__ prev,
    const float* __restrict__ inp,
    const __bf16* __restrict__ wsB,
    const float* __restrict__ bias,
    const int*  __restrict__ act,
    float* __restrict__ out)
{
    const int lane = threadIdx.x & 63;
    const int wv   = threadIdx.x >> 6;   // K-split index, 0..3
    const int m    = lane & 15;
    const int q    = lane >> 4;
    const int row0 = blockIdx.x * 32;    // 32-row M-tile per block
    const int rowA0 = row0 + m;          // sub-tile 0
    const int rowA1 = row0 + 16 + m;     // sub-tile 1

    const float* prow0 = prev + (size_t)rowA0 * NN;
    const float* irow0 = inp  + (size_t)rowA0 * NI;
    const float* prow1 = prev + (size_t)rowA1 * NN;
    const float* irow1 = inp  + (size_t)rowA1 * NI;
    const bf16x8* Bf   = (const bf16x8*)wsB;

    f32x4 acc[2][4];
#pragma unroll
    for (int u = 0; u < 2; ++u)
#pragma unroll
        for (int t = 0; t < 4; ++t)
            acc[u][t] = (f32x4){0.f, 0.f, 0.f, 0.f};

    const int qo = q * 8;

    // 8 K-chunks for this wave, fully unrolled. Per chunk: 4 A-loads (2 rows
    // x 2 float4), 4 B-frag loads (reused by both row-tiles), 8 MFMAs.
#pragma unroll
    for (int i = 0; i < 8; ++i) {
        const int kc = wv * 8 + i;
        const float* s0 = (kc < 4) ? irow0 : prow0;
        const float* s1 = (kc < 4) ? irow1 : prow1;

        const float4* p0 = (const float4*)(s0 + kc * 32 + qo);
        const float4* p1 = (const float4*)(s1 + kc * 32 + qo);
        float4 f00 = p0[0], f01 = p0[1];
        float4 f10 = p1[0], f11 = p1[1];

        bf16x8 a0, a1;
        a0[0] = (__bf16)f00.x; a0[1] = (__bf16)f00.y;
        a0[2] = (__bf16)f00.z; a0[3] = (__bf16)f00.w;
        a0[4] = (__bf16)f01.x; a0[5] = (__bf16)f01.y;
        a0[6] = (__bf16)f01.z; a0[7] = (__bf16)f01.w;
        a1[0] = (__bf16)f10.x; a1[1] = (__bf16)f10.y;
        a1[2] = (__bf16)f10.z; a1[3] = (__bf16)f10.w;
        a1[4] = (__bf16)f11.x; a1[5] = (__bf16)f11.y;
        a1[6] = (__bf16)f11.z; a1[7] = (__bf16)f11.w;

        const bf16x8* bp = Bf + (size_t)kc * 256 + lane;
        bf16x8 b0 = bp[0], b1 = bp[64], b2 = bp[128], b3 = bp[192];

        acc[0][0] = __builtin_amdgcn_mfma_f32_16x16x32_bf16(a0, b0, acc[0][0], 0, 0, 0);
        acc[1][0] = __builtin_amdgcn_mfma_f32_16x16x32_bf16(a1, b0, acc[1][0], 0, 0, 0);
        acc[0][1] = __builtin_amdgcn_mfma_f32_16x16x32_bf16(a0, b1, acc[0][1], 0, 0, 0);
        acc[1][1] = __builtin_amdgcn_mfma_f32_16x16x32_bf16(a1, b1, acc[1][1], 0, 0, 0);
        acc[0][2] = __builtin_amdgcn_mfma_f32_16x16x32_bf16(a0, b2, acc[0][2], 0, 0, 0);
        acc[1][2] = __builtin_amdgcn_mfma_f32_16x16x32_bf16(a1, b2, acc[1][2], 0, 0, 0);
        acc[0][3] = __builtin_amdgcn_mfma_f32_16x16x32_bf16(a0, b3, acc[0][3], 0, 0, 0);
        acc[1][3] = __builtin_amdgcn_mfma_f32_16x16x32_bf16(a1, b3, acc[1][3], 0, 0, 0);
    }

    // ---- Cross-wave K-reduction via LDS ----
    // D layout: col = t*16 + m, row-in-subtile = q*4 + r  [measured m89]
    __shared__ float red[4][32][68];   // [wave][row][col] (+4 pad) = 34 KB
#pragma unroll
    for (int t = 0; t < 4; ++t) {
#pragma unroll
        for (int r = 0; r < 4; ++r) {
            red[wv][q * 4 + r][t * 16 + m]      = acc[0][t][r];
            red[wv][16 + q * 4 + r][t * 16 + m] = acc[1][t][r];
        }
    }
    __syncthreads();

    // Epilogue: 256 threads x 2 float4 each = 32 rows x 64 cols.
    const int orow = threadIdx.x >> 4;          // 0..15
    const int oc   = (threadIdx.x & 15) * 4;    // 0,4,..,60
    const float* bo = bias + (NN - NO);
    const int*   ao = act  + (NN - NO);

#pragma unroll
    for (int h = 0; h < 2; ++h) {
        const int rr = orow + h * 16;
        f32x4 s = *(const f32x4*)&red[0][rr][oc]
                + *(const f32x4*)&red[1][rr][oc]
                + *(const f32x4*)&red[2][rr][oc]
                + *(const f32x4*)&red[3][rr][oc];
        f32x4 o;
#pragma unroll
        for (int c = 0; c < 4; ++c) {
            o[c] = activate(s[c] + bo[oc + c], ao[oc + c]);
        }
        *(f32x4*)(out + (size_t)(row0 + rr) * NO + oc) = o;
    }
}

extern "C" void kernel_launch(void* const* d_in, const int* in_sizes, int n_in,
                              void* d_out, int out_size, void* d_ws, size_t ws_size,
                              hipStream_t stream) {
    const float* prev = (const float*)d_in[0];   // [B, N] fp32
    const float* inp  = (const float*)d_in[1];   // [B, I] fp32
    const float* W    = (const float*)d_in[2];   // [N, N] fp32
    const float* bias = (const float*)d_in[3];   // [N]    fp32
    const int*   act  = (const int*)  d_in[4];   // [N]    int32
    float* out = (float*)d_out;                  // [B, O] fp32
    __bf16* wsB = (__bf16*)d_ws;                 // 65536 bf16 = 128 KB

    // Pack (and pre-scale) W slice into MFMA B-fragment order. ws is re-poisoned
    // by the harness each call, so this runs every launch (~0.5 MB traffic).
    pack_w_kernel<<<256, 256, 0, stream>>>(W, wsB);

    // Main fused kernel: one block per 32-row tile, K-split x4 + M-block x2.
    fused_rnn_kernel<<<BATCH / 32, 256, 0, stream>>>(prev, inp, wsB, bias, act, out);
}